// Round 1
// 2457.462 us; speedup vs baseline: 1.0780x; 1.0780x over previous
//
#include <hip/hip_runtime.h>

// Problem: B=8,H=256,W=256,C=256. pairs = B*H = 2048.
// out[b,h,i,d] = gamma[d]*O + x ; O = softmax_j(Q K^T) V
// Trick 1: QK^T row-softmax == softmax of (X M X^T + u.x_j) with M = Wq Wk^T, u = Wk bq.
// Trick 2: O = A V = A (X Wv) + bv  (softmax rows sum to 1 -> bv folds into epilogue).
// Fully fused kernel per pair:
//   X(bf16) in LDS -> Y=X*M -> S^T=X*Y'^T -> softmax -> A parked COALESCED in out slot
//   -> V computed with m=j orientation from the SAME Xs (B-op = WvT rows, row-major)
//      so each lane holds a j-contiguous V^T run: free transpose, packed in 64 VGPRs
//   -> barrier, overwrite Xs with V^T -> O = A*V^T -> epilogue gamma*(O+bv)+x.
// A store: bounce 16x32 sub-tiles through per-wave scratch -> one dwordx4/wave/ks
// (full 64B lines; kills the 7.3x write amplification + RMW fetch of the old kernel).

#define NPAIR 2048
#define SEQ 256     // W
#define DIM 256     // C
#define XSTR 264    // LDS row stride in bf16 elems (528 B, 16B-aligned, bank-spread)
#define SCRSTR 48   // per-wave scratch row stride (96 B, 16B-aligned)

typedef __attribute__((ext_vector_type(8))) short bf16x8;
typedef __attribute__((ext_vector_type(4))) float f32x4;
typedef __attribute__((ext_vector_type(4))) unsigned uint4v;
typedef __attribute__((ext_vector_type(2))) unsigned uint2v;

__device__ __forceinline__ unsigned short f2bf(float f) {
  union { float f; unsigned u; } v; v.f = f;
  unsigned r = v.u + 0x7FFFu + ((v.u >> 16) & 1u);   // round-to-nearest-even
  return (unsigned short)(r >> 16);
}
__device__ __forceinline__ unsigned pack2(float a, float b) {
  return (unsigned)f2bf(a) | ((unsigned)f2bf(b) << 16);
}

// ---------------- prep: MT = (Wq Wk^T)^T (bf16), u = Wk bq (f32), WvT = Wv^T (bf16)
__global__ void prep_kernel(const float* __restrict__ wq, const float* __restrict__ bq,
                            const float* __restrict__ wk, const float* __restrict__ wv,
                            unsigned short* __restrict__ MT, unsigned short* __restrict__ WvT,
                            float* __restrict__ u) {
  int b = blockIdx.x, t = threadIdx.x;
  if (b < 256) {
    int r = b;  // MT[r][c] = sum_d wq[c][d]*wk[r][d]  == M[c][r]
    for (int c = t; c < 256; c += blockDim.x) {
      float acc = 0.f;
      for (int d = 0; d < 256; ++d) acc += wq[c * 256 + d] * wk[r * 256 + d];
      MT[r * 256 + c] = f2bf(acc);
    }
  } else if (b == 256) {
    for (int cc = t; cc < 256; cc += blockDim.x) {
      float acc = 0.f;
      for (int d = 0; d < 256; ++d) acc += wk[cc * 256 + d] * bq[d];
      u[cc] = acc;
    }
  } else {
    int r = b - 257;  // WvT[r][c] = wv[c][r]
    for (int c = t; c < 256; c += blockDim.x) WvT[r * 256 + c] = f2bf(wv[c * 256 + r]);
  }
}

// ---------------- fused kernel: grid=2048, block=512 (8 waves)
__global__ __launch_bounds__(512, 2)
void attn_fused_kernel(const float* __restrict__ x, const unsigned short* __restrict__ MT,
                       const float* __restrict__ u, const unsigned short* __restrict__ WvT,
                       const float* __restrict__ bv, const float* __restrict__ gamma,
                       float* __restrict__ out) {
  __shared__ unsigned short Xs[SEQ * XSTR];            // 135168 B: X[j][c], later V^T[d][j]
  __shared__ unsigned short Yscr[8][16 * SCRSTR];      // 12288 B, per-wave bounce scratch
  const int p = blockIdx.x;
  const long xbase = (long)p * (SEQ * DIM);
  const int tid = threadIdx.x;
  const int wid = tid >> 6;
  const int ln = tid & 63;
  const int l16 = ln & 15;
  const int quad = ln >> 4;

  // ---- phase 0: stage X -> LDS bf16 (coalesced)
  for (int it = 0; it < 64; ++it) {
    int idx = 2 * (tid + 512 * it);
    float2 v = *(const float2*)(x + xbase + idx);
    int j = idx >> 8, c = idx & 255;
    unsigned pack = (unsigned)f2bf(v.x) | ((unsigned)f2bf(v.y) << 16);
    *(unsigned*)&Xs[j * XSTR + c] = pack;
  }
  __syncthreads();

  float ureg[16];
#pragma unroll
  for (int nt = 0; nt < 16; ++nt) ureg[nt] = u[nt * 16 + l16];

  unsigned short* Aout =
      (unsigned short*)((char*)out + (size_t)p * (SEQ * DIM * 4) + 131072);
  unsigned short* scr = &Yscr[wid][0];

  // ---- phase 1: scores + softmax, A parked coalesced in out-slot upper half
  for (int ch = 0; ch < 2; ++ch) {
    const int chunk = wid + 8 * ch;   // i-chunk 0..15 (16 q-rows each)
    const int i0 = chunk * 16;

    // Y[i][d] = sum_c X[i][c] M[c][d]   (m=i, n=d, k=c)
    f32x4 acc[16];
#pragma unroll
    for (int nt = 0; nt < 16; ++nt) acc[nt] = (f32x4){0.f, 0.f, 0.f, 0.f};
#pragma unroll
    for (int ks = 0; ks < 8; ++ks) {
      bf16x8 a = *(const bf16x8*)&Xs[(i0 + l16) * XSTR + ks * 32 + quad * 8];
#pragma unroll
      for (int nt = 0; nt < 16; ++nt) {
        bf16x8 b = *(const bf16x8*)&MT[(nt * 16 + l16) * 256 + ks * 32 + quad * 8];
        acc[nt] = __builtin_amdgcn_mfma_f32_16x16x32_bf16(a, b, acc[nt], 0, 0, 0);
      }
    }

    // S^T[j][ii] = sum_d X[j][d] * Y'[i0+ii][d]   (m=j, n=ii, k=d), by d-eighths
    f32x4 sacc[16];
#pragma unroll
    for (int mt = 0; mt < 16; ++mt) sacc[mt] = (f32x4){0.f, 0.f, 0.f, 0.f};
#pragma unroll
    for (int e = 0; e < 8; ++e) {
      asm volatile("s_waitcnt lgkmcnt(0)" ::: "memory");
#pragma unroll
      for (int h = 0; h < 2; ++h) {
        int nt = 2 * e + h;
#pragma unroll
        for (int r = 0; r < 4; ++r) {
          float yv = acc[nt][r] + ureg[nt];
          scr[(quad * 4 + r) * SCRSTR + h * 16 + l16] = f2bf(yv);
        }
      }
      asm volatile("s_waitcnt lgkmcnt(0)" ::: "memory");
      bf16x8 bfrag = *(const bf16x8*)&scr[l16 * SCRSTR + quad * 8];
#pragma unroll
      for (int mt = 0; mt < 16; ++mt) {
        bf16x8 a = *(const bf16x8*)&Xs[(mt * 16 + l16) * XSTR + e * 32 + quad * 8];
        sacc[mt] = __builtin_amdgcn_mfma_f32_16x16x32_bf16(a, bfrag, sacc[mt], 0, 0, 0);
      }
    }

    // softmax over j for row ii=l16 (lane holds j = mt*16 + quad*4 + r)
    float mx = -1e30f;
#pragma unroll
    for (int mt = 0; mt < 16; ++mt)
#pragma unroll
      for (int r = 0; r < 4; ++r) mx = fmaxf(mx, sacc[mt][r]);
    mx = fmaxf(mx, __shfl_xor(mx, 16, 64));
    mx = fmaxf(mx, __shfl_xor(mx, 32, 64));
    float sum = 0.f;
#pragma unroll
    for (int mt = 0; mt < 16; ++mt)
#pragma unroll
      for (int r = 0; r < 4; ++r) {
        float ev = exp2f((sacc[mt][r] - mx) * 1.44269504088896340736f);
        sacc[mt][r] = ev;
        sum += ev;
      }
    sum += __shfl_xor(sum, 16, 64);
    sum += __shfl_xor(sum, 32, 64);
    float rs = 1.0f / sum;

    // A store: bounce each 16x32 sub-tile through scratch -> one dwordx4 per lane
    // per ks: 64 lanes x 16B = 16 FULL 64B lines (amplification-free).
#pragma unroll
    for (int ks = 0; ks < 8; ++ks) {
      asm volatile("s_waitcnt lgkmcnt(0)" ::: "memory");   // prev read done (WAR)
#pragma unroll
      for (int h = 0; h < 2; ++h) {
        int mt = 2 * ks + h;
        unsigned lo = pack2(sacc[mt][0] * rs, sacc[mt][1] * rs);
        unsigned hi = pack2(sacc[mt][2] * rs, sacc[mt][3] * rs);
        *(unsigned*)&scr[l16 * SCRSTR + h * 16 + quad * 4] = lo;
        *(unsigned*)&scr[l16 * SCRSTR + h * 16 + quad * 4 + 2] = hi;
      }
      asm volatile("s_waitcnt lgkmcnt(0)" ::: "memory");
      uint4v t = *(const uint4v*)&scr[(ln >> 2) * SCRSTR + (ln & 3) * 8];
      *(uint4v*)&Aout[(i0 + (ln >> 2)) * 256 + ks * 32 + (ln & 3) * 8] = t;
    }
  }
  __syncthreads();   // drains A stores (vmcnt) before anyone reads A back

  // ---- prefetch A for O-phase round 0 (rows 16*wid..+16, written by THIS wave)
  bf16x8 afr[8];
  {
    int i = 16 * wid + l16;
#pragma unroll
    for (int ks = 0; ks < 8; ++ks)
      afr[ks] = *(const bf16x8*)&Aout[i * 256 + ks * 32 + quad * 8];
  }

  // ---- phase 2: V[j][d] = sum_c X[j][c] Wv[c][d]  (m=j, n=d, k=c)
  // C-layout gives lane V[j0+quad*4+r][d0+l16]: j-contiguous at fixed d = a V^T row
  // run. Pack to bf16 in regs; after barrier overwrite Xs with V^T. bv folded into
  // epilogue (softmax rows sum to 1).
  unsigned pay[64];
#pragma unroll
  for (int dc = 0; dc < 16; ++dc) {
    bf16x8 bfr[8];
#pragma unroll
    for (int ks = 0; ks < 8; ++ks)
      bfr[ks] = *(const bf16x8*)&WvT[(dc * 16 + l16) * 256 + ks * 32 + quad * 8];
#pragma unroll
    for (int jr = 0; jr < 2; ++jr) {
      const int jc = wid + 8 * jr;
      f32x4 vacc = (f32x4){0.f, 0.f, 0.f, 0.f};
#pragma unroll
      for (int ks = 0; ks < 8; ++ks) {
        bf16x8 a = *(const bf16x8*)&Xs[(jc * 16 + l16) * XSTR + ks * 32 + quad * 8];
        vacc = __builtin_amdgcn_mfma_f32_16x16x32_bf16(a, bfr[ks], vacc, 0, 0, 0);
      }
      pay[dc * 4 + jr * 2 + 0] = pack2(vacc[0], vacc[1]);
      pay[dc * 4 + jr * 2 + 1] = pack2(vacc[2], vacc[3]);
    }
  }
  __syncthreads();   // all waves done READING Xs
#pragma unroll
  for (int dc = 0; dc < 16; ++dc)
#pragma unroll
    for (int jr = 0; jr < 2; ++jr) {
      const int jc = wid + 8 * jr;
      uint2v w = {pay[dc * 4 + jr * 2], pay[dc * 4 + jr * 2 + 1]};
      *(uint2v*)&Xs[(dc * 16 + l16) * XSTR + jc * 16 + quad * 4] = w;  // V^T[d][j..j+4)
    }
  float greg[16], bvreg[16];
#pragma unroll
  for (int nt = 0; nt < 16; ++nt) {
    greg[nt] = gamma[nt * 16 + l16];
    bvreg[nt] = bv[nt * 16 + l16];
  }
  __syncthreads();   // V^T ready

  // ---- phase 3: O[i][dd] = sum_j A[i][j] V^T[dd][j]  (m=i, n=dd, k=j)
  float* outp = out + (size_t)p * (SEQ * DIM);
  for (int rnd = 0; rnd < 2; ++rnd) {
    const int i0 = (wid + 8 * rnd) * 16;
    f32x4 oacc[16];
#pragma unroll
    for (int nt = 0; nt < 16; ++nt) oacc[nt] = (f32x4){0.f, 0.f, 0.f, 0.f};
#pragma unroll
    for (int ks = 0; ks < 8; ++ks) {
      bf16x8 a = afr[ks];
#pragma unroll
      for (int nt = 0; nt < 16; ++nt) {
        bf16x8 b = *(const bf16x8*)&Xs[(nt * 16 + l16) * XSTR + ks * 32 + quad * 8];
        oacc[nt] = __builtin_amdgcn_mfma_f32_16x16x32_bf16(a, b, oacc[nt], 0, 0, 0);
      }
    }
    if (rnd == 0) {
      // prefetch A for round 1; barrier guarantees all waves' A is in regs before
      // any round-1 out-store can clobber the A region (bytes >= 128K).
      int i = 16 * (8 + wid) + l16;
#pragma unroll
      for (int ks = 0; ks < 8; ++ks)
        afr[ks] = *(const bf16x8*)&Aout[i * 256 + ks * 32 + quad * 8];
      asm volatile("s_waitcnt vmcnt(0)" ::: "memory");
      __syncthreads();
    }
    // epilogue: round-0 rows < 128 -> below A region; round-1 free to clobber.
#pragma unroll
    for (int nt = 0; nt < 16; ++nt)
#pragma unroll
      for (int r = 0; r < 4; ++r) {
        int i = i0 + quad * 4 + r;
        int dd = nt * 16 + l16;
        float xv = x[xbase + (long)i * 256 + dd];
        outp[(long)i * 256 + dd] = greg[nt] * (oacc[nt][r] + bvreg[nt]) + xv;
      }
  }
}

extern "C" void kernel_launch(void* const* d_in, const int* in_sizes, int n_in,
                              void* d_out, int out_size, void* d_ws, size_t ws_size,
                              hipStream_t stream) {
  const float* x     = (const float*)d_in[0];
  const float* wq    = (const float*)d_in[1];
  const float* bq    = (const float*)d_in[2];
  const float* wk    = (const float*)d_in[3];
  // d_in[4] = bk: row-constant in softmax logits -> drops out, unused.
  const float* wv    = (const float*)d_in[5];
  const float* bv    = (const float*)d_in[6];
  const float* gamma = (const float*)d_in[7];
  float* out = (float*)d_out;

  unsigned short* MT  = (unsigned short*)d_ws;   // 131072 B
  unsigned short* WvT = MT + 65536;              // 131072 B
  float* u            = (float*)(WvT + 65536);   // 1024 B   (total 263168 B of ws)

  prep_kernel<<<513, 256, 0, stream>>>(wq, bq, wk, wv, MT, WvT, u);
  attn_fused_kernel<<<NPAIR, 512, 0, stream>>>(x, MT, u, WvT, bv, gamma, out);
}

// Round 2
// 2237.173 us; speedup vs baseline: 1.1841x; 1.0985x over previous
//
#include <hip/hip_runtime.h>

// Problem: B=8,H=256,W=256,C=256. pairs = B*H = 2048.
// out[b,h,i,d] = gamma[d]*O + x ; O = softmax_j(Q K^T) V
// Trick 1: QK^T row-softmax == softmax of (X M X^T + u.x_j) with M = Wq Wk^T, u = Wk bq.
// Trick 2: O = A V = A (X Wv) + bv  (softmax rows sum to 1 -> bv folds into epilogue).
// This round: A NEVER touches HBM. After softmax, A lives packed in 32 VGPRs (bf16
// pairs); O-phase A-fragments are rebuilt per ks through the per-wave LDS scratch
// (same bounce layout the old A-store used: scr[l16][c] = A[i0+l16][ks*32+c], read
// back as bf16x8 at [l16][quad*8]). Also: 1024-thread blocks (16 waves = 4/SIMD,
// occupancy cap 22%->50%); each wave owns one 16-row chunk per phase.
// LDS: Xs 135168 + Yscr 16*768*2 = 159744 B <= 160 KiB (1 block/CU, 16 waves).

#define NPAIR 2048
#define SEQ 256     // W
#define DIM 256     // C
#define XSTR 264    // LDS row stride in bf16 elems (528 B, 16B-aligned, bank-spread)
#define SCRSTR 48   // per-wave scratch row stride (96 B, 16B-aligned)

typedef __attribute__((ext_vector_type(8))) short bf16x8;
typedef __attribute__((ext_vector_type(4))) float f32x4;
typedef __attribute__((ext_vector_type(2))) unsigned uint2v;

__device__ __forceinline__ unsigned short f2bf(float f) {
  union { float f; unsigned u; } v; v.f = f;
  unsigned r = v.u + 0x7FFFu + ((v.u >> 16) & 1u);   // round-to-nearest-even
  return (unsigned short)(r >> 16);
}
__device__ __forceinline__ unsigned pack2(float a, float b) {
  return (unsigned)f2bf(a) | ((unsigned)f2bf(b) << 16);
}

// ---------------- prep: MT = (Wq Wk^T)^T (bf16), u = Wk bq (f32), WvT = Wv^T (bf16)
__global__ void prep_kernel(const float* __restrict__ wq, const float* __restrict__ bq,
                            const float* __restrict__ wk, const float* __restrict__ wv,
                            unsigned short* __restrict__ MT, unsigned short* __restrict__ WvT,
                            float* __restrict__ u) {
  int b = blockIdx.x, t = threadIdx.x;
  if (b < 256) {
    int r = b;  // MT[r][c] = sum_d wq[c][d]*wk[r][d]  == M[c][r]
    for (int c = t; c < 256; c += blockDim.x) {
      float acc = 0.f;
      for (int d = 0; d < 256; ++d) acc += wq[c * 256 + d] * wk[r * 256 + d];
      MT[r * 256 + c] = f2bf(acc);
    }
  } else if (b == 256) {
    for (int cc = t; cc < 256; cc += blockDim.x) {
      float acc = 0.f;
      for (int d = 0; d < 256; ++d) acc += wk[cc * 256 + d] * bq[d];
      u[cc] = acc;
    }
  } else {
    int r = b - 257;  // WvT[r][c] = wv[c][r]
    for (int c = t; c < 256; c += blockDim.x) WvT[r * 256 + c] = f2bf(wv[c * 256 + r]);
  }
}

// ---------------- fused kernel: grid=2048, block=1024 (16 waves, 4/SIMD)
__global__ __launch_bounds__(1024, 4)
void attn_fused_kernel(const float* __restrict__ x, const unsigned short* __restrict__ MT,
                       const float* __restrict__ u, const unsigned short* __restrict__ WvT,
                       const float* __restrict__ bv, const float* __restrict__ gamma,
                       float* __restrict__ out) {
  __shared__ unsigned short Xs[SEQ * XSTR];            // 135168 B: X[j][c], later V^T[d][j]
  __shared__ unsigned short Yscr[16][16 * SCRSTR];     // 24576 B, per-wave bounce scratch
  const int p = blockIdx.x;
  const long xbase = (long)p * (SEQ * DIM);
  const int tid = threadIdx.x;
  const int wid = tid >> 6;      // 0..15
  const int ln = tid & 63;
  const int l16 = ln & 15;
  const int quad = ln >> 4;
  const int i0 = wid * 16;       // this wave's 16-row chunk (queries / j-chunk / out rows)

  // ---- phase 0: stage X -> LDS bf16 (float4 loads, 8B LDS writes, coalesced)
  for (int it = 0; it < 16; ++it) {
    int idx = 4 * (tid + 1024 * it);
    float4 v = *(const float4*)(x + xbase + idx);
    int j = idx >> 8, c = idx & 255;
    uint2v w = {pack2(v.x, v.y), pack2(v.z, v.w)};
    *(uint2v*)&Xs[j * XSTR + c] = w;
  }
  __syncthreads();

  float ureg[16];
#pragma unroll
  for (int nt = 0; nt < 16; ++nt) ureg[nt] = u[nt * 16 + l16];

  unsigned short* scr = &Yscr[wid][0];

  // ---- phase 1a: Y[i][d] = sum_c X[i][c] M[c][d]   (m=i, n=d, k=c)
  f32x4 acc[16];
#pragma unroll
  for (int nt = 0; nt < 16; ++nt) acc[nt] = (f32x4){0.f, 0.f, 0.f, 0.f};
#pragma unroll
  for (int ks = 0; ks < 8; ++ks) {
    bf16x8 a = *(const bf16x8*)&Xs[(i0 + l16) * XSTR + ks * 32 + quad * 8];
#pragma unroll
    for (int nt = 0; nt < 16; ++nt) {
      bf16x8 b = *(const bf16x8*)&MT[(nt * 16 + l16) * 256 + ks * 32 + quad * 8];
      acc[nt] = __builtin_amdgcn_mfma_f32_16x16x32_bf16(a, b, acc[nt], 0, 0, 0);
    }
  }

  // ---- phase 1b: S^T[j][ii] = sum_d X[j][d] * Y'[i0+ii][d]  (m=j, n=ii, k=d)
  f32x4 sacc[16];
#pragma unroll
  for (int mt = 0; mt < 16; ++mt) sacc[mt] = (f32x4){0.f, 0.f, 0.f, 0.f};
#pragma unroll
  for (int e = 0; e < 8; ++e) {
    asm volatile("s_waitcnt lgkmcnt(0)" ::: "memory");   // WAR on scratch
#pragma unroll
    for (int h = 0; h < 2; ++h) {
      int nt = 2 * e + h;
#pragma unroll
      for (int r = 0; r < 4; ++r) {
        float yv = acc[nt][r] + ureg[nt];
        scr[(quad * 4 + r) * SCRSTR + h * 16 + l16] = f2bf(yv);
      }
    }
    asm volatile("s_waitcnt lgkmcnt(0)" ::: "memory");
    bf16x8 bfrag = *(const bf16x8*)&scr[l16 * SCRSTR + quad * 8];
#pragma unroll
    for (int mt = 0; mt < 16; ++mt) {
      bf16x8 a = *(const bf16x8*)&Xs[(mt * 16 + l16) * XSTR + e * 32 + quad * 8];
      sacc[mt] = __builtin_amdgcn_mfma_f32_16x16x32_bf16(a, bfrag, sacc[mt], 0, 0, 0);
    }
  }

  // ---- softmax over j for row i0+l16 (lane holds j = mt*16 + quad*4 + r)
  float mx = -1e30f;
#pragma unroll
  for (int mt = 0; mt < 16; ++mt)
#pragma unroll
    for (int r = 0; r < 4; ++r) mx = fmaxf(mx, sacc[mt][r]);
  mx = fmaxf(mx, __shfl_xor(mx, 16, 64));
  mx = fmaxf(mx, __shfl_xor(mx, 32, 64));
  float sum = 0.f;
#pragma unroll
  for (int mt = 0; mt < 16; ++mt)
#pragma unroll
    for (int r = 0; r < 4; ++r) {
      float ev = exp2f((sacc[mt][r] - mx) * 1.44269504088896340736f);
      sacc[mt][r] = ev;
      sum += ev;
    }
  sum += __shfl_xor(sum, 16, 64);
  sum += __shfl_xor(sum, 32, 64);
  float rs = 1.0f / sum;

  // ---- pack A into 32 VGPRs: aw[2mt] = A[i][16mt+4quad+{0,1}], aw[2mt+1] = +{2,3}
  unsigned aw[32];
#pragma unroll
  for (int mt = 0; mt < 16; ++mt) {
    aw[2 * mt]     = pack2(sacc[mt][0] * rs, sacc[mt][1] * rs);
    aw[2 * mt + 1] = pack2(sacc[mt][2] * rs, sacc[mt][3] * rs);
  }

  // ---- phase 2: V[j][d] = sum_c X[j][c] Wv[c][d]  (m=j, n=d, k=c), j-chunk = wid.
  // C-layout gives lane V[i0+quad*4+r][d0+l16]: j-contiguous at fixed d -> free
  // transpose into V^T rows. bv folded into epilogue (softmax rows sum to 1).
  bf16x8 axr[8];
#pragma unroll
  for (int ks = 0; ks < 8; ++ks)
    axr[ks] = *(const bf16x8*)&Xs[(i0 + l16) * XSTR + ks * 32 + quad * 8];
  unsigned pay[32];
#pragma unroll
  for (int dc = 0; dc < 16; ++dc) {
    f32x4 vacc = (f32x4){0.f, 0.f, 0.f, 0.f};
#pragma unroll
    for (int ks = 0; ks < 8; ++ks) {
      bf16x8 b = *(const bf16x8*)&WvT[(dc * 16 + l16) * 256 + ks * 32 + quad * 8];
      vacc = __builtin_amdgcn_mfma_f32_16x16x32_bf16(axr[ks], b, vacc, 0, 0, 0);
    }
    pay[2 * dc]     = pack2(vacc[0], vacc[1]);
    pay[2 * dc + 1] = pack2(vacc[2], vacc[3]);
  }
  __syncthreads();   // ALL waves done reading Xs as X (phase 1 + phase 2)

#pragma unroll
  for (int dc = 0; dc < 16; ++dc) {
    uint2v w = {pay[2 * dc], pay[2 * dc + 1]};
    *(uint2v*)&Xs[(dc * 16 + l16) * XSTR + i0 + quad * 4] = w;  // V^T[d][j..j+4)
  }
  float greg[16], bvreg[16];
#pragma unroll
  for (int nt = 0; nt < 16; ++nt) {
    greg[nt] = gamma[nt * 16 + l16];
    bvreg[nt] = bv[nt * 16 + l16];
  }
  __syncthreads();   // V^T ready

  // ---- phase 3: O[i][dd] = sum_j A[i][j] V^T[dd][j]  (m=i, n=dd, k=j).
  // A-fragment per ks rebuilt through per-wave scratch: write aw -> scr (layout
  // scr[l16][c] = A[i0+l16][ks*32+c]), read bf16x8 at [l16][quad*8].
  f32x4 oacc[16];
#pragma unroll
  for (int nt = 0; nt < 16; ++nt) oacc[nt] = (f32x4){0.f, 0.f, 0.f, 0.f};
#pragma unroll
  for (int ks = 0; ks < 8; ++ks) {
    asm volatile("s_waitcnt lgkmcnt(0)" ::: "memory");   // WAR: prev afrag read done
    uint2v w0 = {aw[4 * ks], aw[4 * ks + 1]};
    uint2v w1 = {aw[4 * ks + 2], aw[4 * ks + 3]};
    *(uint2v*)&scr[l16 * SCRSTR + quad * 4] = w0;          // h=0 half (cols 0..15)
    *(uint2v*)&scr[l16 * SCRSTR + 16 + quad * 4] = w1;     // h=1 half (cols 16..31)
    asm volatile("s_waitcnt lgkmcnt(0)" ::: "memory");
    bf16x8 afrag = *(const bf16x8*)&scr[l16 * SCRSTR + quad * 8];
#pragma unroll
    for (int nt = 0; nt < 16; ++nt) {
      bf16x8 b = *(const bf16x8*)&Xs[(nt * 16 + l16) * XSTR + ks * 32 + quad * 8];
      oacc[nt] = __builtin_amdgcn_mfma_f32_16x16x32_bf16(afrag, b, oacc[nt], 0, 0, 0);
    }
  }

  // ---- epilogue: out = gamma*(O + bv) + x
  float* outp = out + (size_t)p * (SEQ * DIM);
#pragma unroll
  for (int nt = 0; nt < 16; ++nt)
#pragma unroll
    for (int r = 0; r < 4; ++r) {
      int i = i0 + quad * 4 + r;
      int dd = nt * 16 + l16;
      float xv = x[xbase + (long)i * 256 + dd];
      outp[(long)i * 256 + dd] = greg[nt] * (oacc[nt][r] + bvreg[nt]) + xv;
    }
}

extern "C" void kernel_launch(void* const* d_in, const int* in_sizes, int n_in,
                              void* d_out, int out_size, void* d_ws, size_t ws_size,
                              hipStream_t stream) {
  const float* x     = (const float*)d_in[0];
  const float* wq    = (const float*)d_in[1];
  const float* bq    = (const float*)d_in[2];
  const float* wk    = (const float*)d_in[3];
  // d_in[4] = bk: row-constant in softmax logits -> drops out, unused.
  const float* wv    = (const float*)d_in[5];
  const float* bv    = (const float*)d_in[6];
  const float* gamma = (const float*)d_in[7];
  float* out = (float*)d_out;

  unsigned short* MT  = (unsigned short*)d_ws;   // 131072 B
  unsigned short* WvT = MT + 65536;              // 131072 B
  float* u            = (float*)(WvT + 65536);   // 1024 B   (total 263168 B of ws)

  prep_kernel<<<513, 256, 0, stream>>>(wq, bq, wk, wv, MT, WvT, u);
  attn_fused_kernel<<<NPAIR, 1024, 0, stream>>>(x, MT, u, WvT, bv, gamma, out);
}